// Round 1
// baseline (2892.296 us; speedup 1.0000x reference)
//
#include <hip/hip_runtime.h>

// GRU scan: T=128 steps, N=1024 batch, H=512 hidden, I=64 input.
// Step t: A = [h*m | x*m] (1024 x 576) fp16, W16 = [W_hh | W_ih] (1536 x 576) fp16.
// Gates r,z: combined K=576 accumulation. Gate n: separate h_n (K=0..511) and
// i_n (K=512..575) accumulators because n = tanh(i_n + r*h_n).
// h for step t is read from d_out slot t-1 (exactly h_new of previous step).

#define T_STEPS 128
#define NBATCH  1024
#define HDIM    512
#define IDIM    64
#define KTOT    576
#define BM      64
#define BN      32
#define LDP     40   // padded LDS row stride in halves (breaks pow2 bank aliasing)

typedef _Float16 half8  __attribute__((ext_vector_type(8)));
typedef float    floatx4 __attribute__((ext_vector_type(4)));

__global__ void prep_w_kernel(const float* __restrict__ Whh,
                              const float* __restrict__ Wih,
                              _Float16* __restrict__ W16) {
    int idx = blockIdx.x * 256 + threadIdx.x;
    if (idx >= 1536 * KTOT) return;
    int c = idx / KTOT;
    int k = idx - c * KTOT;
    float v = (k < HDIM) ? Whh[c * HDIM + k] : Wih[c * IDIM + (k - HDIM)];
    W16[idx] = (_Float16)v;
}

__device__ __forceinline__ float sigmoidf_(float x) {
    return 1.0f / (1.0f + __expf(-x));
}

__global__ __launch_bounds__(256)
void gru_step_kernel(const float* __restrict__ h_prev,   // [N,H] fp32
                     const float* __restrict__ x_t,      // [N,I] fp32
                     const float* __restrict__ m_t,      // [N]   fp32
                     const _Float16* __restrict__ W16,   // [1536,576] fp16
                     const float* __restrict__ b_ih,     // [1536]
                     const float* __restrict__ b_hh,     // [1536]
                     float* __restrict__ out_x,          // [N,H] fp32 (out slot t)
                     float* __restrict__ out_h) {        // [N,H] or null (h_final)
    __shared__ __align__(16) _Float16 As[BM * LDP];
    __shared__ __align__(16) _Float16 Bs[3][BN * LDP];

    const int tid = threadIdx.x;
    const int rt = blockIdx.x >> 4;   // 16 row tiles of 64
    const int ctile = blockIdx.x & 15; // 16 col tiles of 32
    const int rowbase = rt * BM;
    const int colbase = ctile * BN;

    // A staging mapping: 4 threads per row, 8 consecutive k each
    const int arow = tid >> 2;          // 0..63
    const int ak0  = (tid & 3) * 8;     // 0,8,16,24
    const float maskv = m_t[rowbase + arow];

    const int wave = tid >> 6;          // 0..3 -> row sub-tile of 16
    const int lane = tid & 63;
    const int n16  = lane & 15;
    const int q    = lane >> 4;

    floatx4 acc_r[2], acc_z[2], acc_hn[2], acc_in[2];
#pragma unroll
    for (int bt = 0; bt < 2; ++bt) {
        acc_r[bt] = (floatx4){0.f, 0.f, 0.f, 0.f};
        acc_z[bt] = (floatx4){0.f, 0.f, 0.f, 0.f};
        acc_hn[bt] = (floatx4){0.f, 0.f, 0.f, 0.f};
        acc_in[bt] = (floatx4){0.f, 0.f, 0.f, 0.f};
    }

    for (int kt = 0; kt < 18; ++kt) {
        const int kbase = kt * 32;

        // ---- stage A tile: 64 rows x 32 k, fp32 -> (*mask) -> fp16
        const float* asrc;
        if (kt < 16) {
            asrc = h_prev + (size_t)(rowbase + arow) * HDIM + kbase + ak0;
        } else {
            asrc = x_t + (size_t)(rowbase + arow) * IDIM + (kbase - HDIM) + ak0;
        }
        floatx4 a0 = *(const floatx4*)asrc;
        floatx4 a1 = *(const floatx4*)(asrc + 4);
        half8 av;
        av[0] = (_Float16)(a0.x * maskv);
        av[1] = (_Float16)(a0.y * maskv);
        av[2] = (_Float16)(a0.z * maskv);
        av[3] = (_Float16)(a0.w * maskv);
        av[4] = (_Float16)(a1.x * maskv);
        av[5] = (_Float16)(a1.y * maskv);
        av[6] = (_Float16)(a1.z * maskv);
        av[7] = (_Float16)(a1.w * maskv);
        *(half8*)&As[arow * LDP + ak0] = av;

        // ---- stage B tiles: 3 gates x 32 rows x 32 k fp16 (already fp16 in ws)
        // 384 16B-chunks, 256 threads
#pragma unroll
        for (int ii = 0; ii < 2; ++ii) {
            int idx = tid + ii * 256;
            if (idx < 384) {
                int g    = idx >> 7;        // 0..2
                int rem  = idx & 127;
                int brow = rem >> 2;        // 0..31
                int bk0  = (rem & 3) * 8;
                const _Float16* bsrc =
                    W16 + (size_t)(g * HDIM + colbase + brow) * KTOT + kbase + bk0;
                *(half8*)&Bs[g][brow * LDP + bk0] = *(const half8*)bsrc;
            }
        }
        __syncthreads();

        // ---- MFMA
        half8 af = *(const half8*)&As[(wave * 16 + n16) * LDP + q * 8];
#pragma unroll
        for (int bt = 0; bt < 2; ++bt) {
            half8 br = *(const half8*)&Bs[0][(bt * 16 + n16) * LDP + q * 8];
            half8 bz = *(const half8*)&Bs[1][(bt * 16 + n16) * LDP + q * 8];
            half8 bn = *(const half8*)&Bs[2][(bt * 16 + n16) * LDP + q * 8];
            acc_r[bt] = __builtin_amdgcn_mfma_f32_16x16x32_f16(af, br, acc_r[bt], 0, 0, 0);
            acc_z[bt] = __builtin_amdgcn_mfma_f32_16x16x32_f16(af, bz, acc_z[bt], 0, 0, 0);
            if (kt < 16) {
                acc_hn[bt] = __builtin_amdgcn_mfma_f32_16x16x32_f16(af, bn, acc_hn[bt], 0, 0, 0);
            } else {
                acc_in[bt] = __builtin_amdgcn_mfma_f32_16x16x32_f16(af, bn, acc_in[bt], 0, 0, 0);
            }
        }
        __syncthreads();
    }

    // ---- epilogue: gates -> h_new
    // C/D layout: col = lane&15, row = (lane>>4)*4 + reg  (dtype-independent, HW-verified)
#pragma unroll
    for (int bt = 0; bt < 2; ++bt) {
        const int c = colbase + bt * 16 + n16;
        const float brb = b_ih[c] + b_hh[c];
        const float bzb = b_ih[c + HDIM] + b_hh[c + HDIM];
        const float bin = b_ih[c + 2 * HDIM];
        const float bhn = b_hh[c + 2 * HDIM];
#pragma unroll
        for (int r = 0; r < 4; ++r) {
            const int i = rowbase + wave * 16 + q * 4 + r;
            const float rg = sigmoidf_(acc_r[bt][r] + brb);
            const float zg = sigmoidf_(acc_z[bt][r] + bzb);
            const float ng = tanhf(acc_in[bt][r] + bin + rg * (acc_hn[bt][r] + bhn));
            const float hm = h_prev[(size_t)i * HDIM + c] * m_t[i];
            const float hv = (1.0f - zg) * ng + zg * hm;
            out_x[(size_t)i * HDIM + c] = hv;
            if (out_h) out_h[(size_t)i * HDIM + c] = hv;
        }
    }
}

extern "C" void kernel_launch(void* const* d_in, const int* in_sizes, int n_in,
                              void* d_out, int out_size, void* d_ws, size_t ws_size,
                              hipStream_t stream) {
    const float* hxs   = (const float*)d_in[0];
    // d_in[1] = gru_init: dead code in the reference, unused
    const float* masks = (const float*)d_in[2];
    const float* pact  = (const float*)d_in[3];
    const float* W_ih  = (const float*)d_in[4];
    const float* W_hh  = (const float*)d_in[5];
    const float* b_ih  = (const float*)d_in[6];
    const float* b_hh  = (const float*)d_in[7];
    float* out = (float*)d_out;
    _Float16* W16 = (_Float16*)d_ws;   // 1536*576*2 = 1.77 MB

    const int wtot = 1536 * KTOT;
    prep_w_kernel<<<(wtot + 255) / 256, 256, 0, stream>>>(W_hh, W_ih, W16);

    for (int t = 0; t < T_STEPS; ++t) {
        const float* h_prev =
            (t == 0) ? hxs : out + (size_t)(t - 1) * NBATCH * HDIM;
        float* out_x = out + (size_t)t * NBATCH * HDIM;
        float* out_h =
            (t == T_STEPS - 1) ? out + (size_t)T_STEPS * NBATCH * HDIM : nullptr;
        gru_step_kernel<<<256, 256, 0, stream>>>(
            h_prev, pact + (size_t)t * NBATCH * IDIM, masks + (size_t)t * NBATCH,
            W16, b_ih, b_hh, out_x, out_h);
    }
}